// Round 12
// baseline (1101.893 us; speedup 1.0000x reference)
//
#include <hip/hip_runtime.h>

// Neighbor aggregation: out[b, dst] += w * H[b, src], H rows = 256 fp32.
// R12 = R11 with the nontemporal-store type fixed (bucket entries packed as
// u64, not uint2). Two-pass RADIX scatter:
//  pass1 (fused with H->fp16 cvt): append packed (rec<<32|dst) to 256 coarse
//    dst-range buckets per batch (hot tail lines, L2-friendly). Buckets live
//    in d_out (dead until agg overwrites it).
//  pass2: one block per (b,bucket): LDS cursors for its ~196 nodes, writes
//    cap-32 segments into a ~25KB window owned by one CU, then writes the
//    per-node degree array coalesced.
// Aggregate (unchanged, compulsory-miss wall ~220us): one wave per (b,node),
// one-line segment read, 8-deep gather pipeline, fp32 acc, nt stores.

constexpr int ROW = 256;        // HS*HS
constexpr int CAP = 32;         // records per (b,dst) segment = one 128B line
constexpr int NBKT = 256;       // coarse dst-range buckets per batch
constexpr int BKCAP = 8192;     // entries per bucket (mean 3125, 90 sigma)
constexpr int OVFCAP = 65536;   // deg>CAP overflow edges (expect ~150)
constexpr int MAXBSZ = 512;     // max nodes per bucket (LDS cursor array)

typedef _Float16 half4 __attribute__((ext_vector_type(4)));
typedef float fvec4 __attribute__((ext_vector_type(4)));

static __device__ inline float h2f_bits(unsigned short u) {
    _Float16 h; __builtin_memcpy(&h, &u, 2); return (float)h;
}

__global__ void k_init(const int* __restrict__ nidx, int* __restrict__ inv,
                       int* __restrict__ zbuf, int nz, int N) {
    int i = blockIdx.x * blockDim.x + threadIdx.x;
    if (i < N) inv[nidx[i]] = i;
    if (i < nz) zbuf[i] = 0;
}

// pass1 + cvt, per-wave sequential: scatter edges into coarse buckets, then
// stream-convert H to fp16. Waves that finish scatter early start cvt.
__global__ __launch_bounds__(256)
void k_prep1(const fvec4* __restrict__ H, half4* __restrict__ Hh, size_t n4,
             const unsigned long long* __restrict__ ei, const float* __restrict__ ew,
             const int* __restrict__ inv, int* __restrict__ bktcnt,
             unsigned long long* __restrict__ bkt, int B, int E, int N, int bucketSz) {
    size_t tid0 = (size_t)blockIdx.x * 256 + threadIdx.x;
    size_t stride = (size_t)gridDim.x * 256;
    long long total = (long long)B * E;
    for (long long idx = (long long)tid0; idx < total; idx += (long long)stride) {
        int i = (int)idx;
        unsigned long long pq = __builtin_nontemporal_load(&ei[i]);
        int b = i / E;
        int dst = inv[(int)(pq & 0xFFFFFFFFull)];
        int src = inv[(int)(pq >> 32)];
        float w = __builtin_nontemporal_load(&ew[i]);
        _Float16 hw = (_Float16)w;
        unsigned short wb; __builtin_memcpy(&wb, &hw, 2);
        unsigned rec = (unsigned)(unsigned short)src | ((unsigned)wb << 16);
        int q = dst / bucketSz;
        int bq = b * NBKT + q;
        int pos = atomicAdd(&bktcnt[bq], 1);
        if (pos < BKCAP) {
            unsigned long long e = ((unsigned long long)rec << 32) | (unsigned)dst;
            __builtin_nontemporal_store(e, &bkt[(size_t)bq * BKCAP + pos]);
        }
        // bucket overflow statistically impossible (90 sigma); dropped if so
    }
    for (size_t i = tid0; i < n4; i += stride) {
        fvec4 v = __builtin_nontemporal_load(&H[i]);
        half4 o;
        o.x = (_Float16)v.x; o.y = (_Float16)v.y;
        o.z = (_Float16)v.z; o.w = (_Float16)v.w;
        Hh[i] = o;   // cacheable: this IS the gather working set
    }
}

// pass2: one block per (b,bucket). LDS cursors; segments written into a
// ~25KB window owned by this CU; degree array written coalesced.
__global__ __launch_bounds__(256)
void k_pass2(const unsigned long long* __restrict__ bkt, const int* __restrict__ bktcnt,
             unsigned* __restrict__ edges, int* __restrict__ cursor,
             int* __restrict__ ovfcnt, uint2* __restrict__ ovf,
             int B, int N, int bucketSz) {
    __shared__ int lcur[MAXBSZ];
    int bq = blockIdx.x;
    int b = bq / NBKT;
    int q = bq % NBKT;
    int base = q * bucketSz;
    int nloc = min(bucketSz, N - base);
    if (nloc <= 0) return;
    for (int t = threadIdx.x; t < nloc; t += 256) lcur[t] = 0;
    __syncthreads();
    int cnt = bktcnt[bq];
    if (cnt > BKCAP) cnt = BKCAP;
    for (int i = threadIdx.x; i < cnt; i += 256) {
        unsigned long long e = bkt[(size_t)bq * BKCAP + i];
        int dst = (int)(e & 0xFFFFFFFFull);
        unsigned rec = (unsigned)(e >> 32);
        int pos = atomicAdd(&lcur[dst - base], 1);
        if (pos < CAP) {
            __builtin_nontemporal_store(rec, &edges[((size_t)b * N + dst) * CAP + pos]);
        } else {
            int op = atomicAdd(ovfcnt, 1);
            if (op < OVFCAP)
                ovf[op] = make_uint2(((unsigned)b << 16) | (unsigned)dst, rec);
        }
    }
    __syncthreads();
    for (int t = threadIdx.x; t < nloc; t += 256)
        cursor[(size_t)b * N + base + t] = lcur[t];
}

__device__ inline void fma4(fvec4& acc, float w, half4 h) {
    acc.x += w * (float)h.x; acc.y += w * (float)h.y;
    acc.z += w * (float)h.z; acc.w += w * (float)h.w;
}

// xpb > 0: XCD-partitioned flat grid. xcd = bi&7 owns batch b = xcd/xpb;
// group index k = (bi>>3)*xpb + (xcd%xpb).
__global__ __launch_bounds__(256)
void k_agg_gap(const _Float16* __restrict__ Hh, const int* __restrict__ cursor,
               const unsigned* __restrict__ edges, float* __restrict__ out,
               int B, int N, int xpb) {
    int lane = threadIdx.x & 63;
    int wid = threadIdx.x >> 6;
    int b, grp;
    if (xpb > 0) {
        int bi = blockIdx.x;
        int xcd = bi & 7;
        b = xcd / xpb;
        grp = (bi >> 3) * xpb + (xcd % xpb);
    } else {
        b = blockIdx.y;
        grp = blockIdx.x;
    }
    int node = grp * 4 + wid;
    if (node >= N) return;
    size_t sidx = (size_t)b * N + node;
    int deg = cursor[sidx];
    if (deg > CAP) deg = CAP;
    const unsigned* seg = edges + sidx * CAP;
    unsigned rec = 0;
    if (lane < deg) rec = __builtin_nontemporal_load(&seg[lane]);  // one 128B line
    const half4* Hb = (const half4*)(Hh + (size_t)b * N * ROW);
    fvec4 acc = {0.f, 0.f, 0.f, 0.f};
    int j = 0;
    for (; j + 8 <= deg; j += 8) {
        int sv[8]; float wv[8];
#pragma unroll
        for (int u = 0; u < 8; ++u) {
            unsigned r = __shfl(rec, j + u);
            sv[u] = (int)(r & 0xFFFFu);
            wv[u] = h2f_bits((unsigned short)(r >> 16));
        }
        half4 hv[8];
#pragma unroll
        for (int u = 0; u < 8; ++u) hv[u] = Hb[(size_t)sv[u] * 64 + lane];
#pragma unroll
        for (int u = 0; u < 8; ++u) fma4(acc, wv[u], hv[u]);
    }
    if (j + 4 <= deg) {
        int sv[4]; float wv[4];
#pragma unroll
        for (int u = 0; u < 4; ++u) {
            unsigned r = __shfl(rec, j + u);
            sv[u] = (int)(r & 0xFFFFu);
            wv[u] = h2f_bits((unsigned short)(r >> 16));
        }
        half4 hv[4];
#pragma unroll
        for (int u = 0; u < 4; ++u) hv[u] = Hb[(size_t)sv[u] * 64 + lane];
#pragma unroll
        for (int u = 0; u < 4; ++u) fma4(acc, wv[u], hv[u]);
        j += 4;
    }
    for (; j < deg; ++j) {
        unsigned r = __shfl(rec, j);
        half4 h = Hb[(size_t)(r & 0xFFFFu) * 64 + lane];
        fma4(acc, h2f_bits((unsigned short)(r >> 16)), h);
    }
    __builtin_nontemporal_store(acc, (fvec4*)out + (sidx * 64 + lane));
}

// Apply rare cap-overflow edges with fp32 atomics (runs after k_agg_gap).
__global__ __launch_bounds__(256)
void k_ovf(const _Float16* __restrict__ Hh, const int* __restrict__ ovfcnt,
           const uint2* __restrict__ ovf, float* __restrict__ out, int N) {
    int lane = threadIdx.x & 63;
    int wv = (blockIdx.x * 256 + (int)threadIdx.x) >> 6;
    int nw = gridDim.x * 4;
    int count = *ovfcnt;
    if (count > OVFCAP) count = OVFCAP;
    for (int i = wv; i < count; i += nw) {
        uint2 v = ovf[i];
        int b = (int)(v.x >> 16);
        int dst = (int)(v.x & 0xFFFFu);
        int src = (int)(v.y & 0xFFFFu);
        float w = h2f_bits((unsigned short)(v.y >> 16));
        half4 h = ((const half4*)(Hh + (size_t)b * N * ROW))[(size_t)src * 64 + lane];
        float* op = out + ((size_t)b * N + dst) * ROW + lane * 4;
        atomicAdd(op + 0, w * (float)h.x);
        atomicAdd(op + 1, w * (float)h.y);
        atomicAdd(op + 2, w * (float)h.z);
        atomicAdd(op + 3, w * (float)h.w);
    }
}

// ---- R9 role-split prep (fallback if radix preconditions fail) ----
__global__ __launch_bounds__(256)
void k_prep_rs(const fvec4* __restrict__ H, half4* __restrict__ Hh, size_t n4,
               int cvtBlocks, int scatBlocks,
               const unsigned long long* __restrict__ ei, const float* __restrict__ ew,
               const int* __restrict__ inv, int* __restrict__ cursor,
               unsigned* __restrict__ edges, int* __restrict__ ovfcnt,
               uint2* __restrict__ ovf, int B, int E, int N) {
    if ((int)blockIdx.x < cvtBlocks) {
        size_t stride = (size_t)cvtBlocks * 256;
        for (size_t i = (size_t)blockIdx.x * 256 + threadIdx.x; i < n4; i += stride) {
            fvec4 v = __builtin_nontemporal_load(&H[i]);
            half4 o;
            o.x = (_Float16)v.x; o.y = (_Float16)v.y;
            o.z = (_Float16)v.z; o.w = (_Float16)v.w;
            Hh[i] = o;
        }
    } else {
        int total = B * E;
        int stride = scatBlocks * 256;
        for (int idx = ((int)blockIdx.x - cvtBlocks) * 256 + (int)threadIdx.x;
             idx < total; idx += stride) {
            unsigned long long pq = __builtin_nontemporal_load(&ei[idx]);
            int b = idx / E;
            int dst = inv[(int)(pq & 0xFFFFFFFFull)];
            int src = inv[(int)(pq >> 32)];
            float w = __builtin_nontemporal_load(&ew[idx]);
            _Float16 hw = (_Float16)w;
            unsigned short wb; __builtin_memcpy(&wb, &hw, 2);
            unsigned rec = (unsigned)(unsigned short)src | ((unsigned)wb << 16);
            size_t sidx = (size_t)b * N + dst;
            int pos = atomicAdd(&cursor[sidx], 1);
            if (pos < CAP) {
                __builtin_nontemporal_store(rec, &edges[sidx * CAP + pos]);
            } else {
                int op = atomicAdd(ovfcnt, 1);
                if (op < OVFCAP)
                    ovf[op] = make_uint2(((unsigned)b << 16) | (unsigned)dst, rec);
            }
        }
    }
}

// ---- minimal-workspace fallback ----
__global__ void k_zero_f32(float* __restrict__ p, size_t n) {
    size_t i = (size_t)blockIdx.x * blockDim.x + threadIdx.x;
    if (i < n) p[i] = 0.f;
}

__global__ void k_atomic_agg(const float* __restrict__ H, const int* __restrict__ ei,
                             const float* __restrict__ ew, const int* __restrict__ inv,
                             float* __restrict__ out, int B, int E, int N) {
    int lane = threadIdx.x & 63;
    int widx = (blockIdx.x * blockDim.x + threadIdx.x) >> 6;
    int total = B * E;
    if (widx >= total) return;
    int b = widx / E;
    int d = ei[(size_t)widx * 2];
    int s = ei[(size_t)widx * 2 + 1];
    if (inv) { d = inv[d]; s = inv[s]; }
    float w = ew[widx];
    const float4* hp = (const float4*)(H + ((size_t)b * N + s) * ROW);
    float4 h = hp[lane];
    float* op = out + ((size_t)b * N + d) * ROW + lane * 4;
    atomicAdd(op + 0, w * h.x);
    atomicAdd(op + 1, w * h.y);
    atomicAdd(op + 2, w * h.z);
    atomicAdd(op + 3, w * h.w);
}

static inline size_t alignup(size_t x) { return (x + 255) & ~(size_t)255; }

extern "C" void kernel_launch(void* const* d_in, const int* in_sizes, int n_in,
                              void* d_out, int out_size, void* d_ws, size_t ws_size,
                              hipStream_t stream) {
    const float* H = (const float*)d_in[0];
    const int* ei = (const int*)d_in[1];
    const float* ew = (const float*)d_in[2];
    const int* nidx = (const int*)d_in[3];
    float* out = (float*)d_out;

    int N = in_sizes[3];                    // 50000
    int B = in_sizes[0] / (N * ROW);        // 4
    int E = in_sizes[2] / B;                // 800000
    int total = B * E;
    size_t nH = (size_t)B * N * ROW;
    char* w0 = (char*)d_ws;
    int bucketSz = (N + NBKT - 1) / NBKT;   // 196

    // ---- ws layout: inv | cursor(B*N)+ovfcnt+bktcnt(B*NBKT) | ovf | seg | Hh
    size_t o_inv = 0;
    size_t o_cur = alignup(o_inv + (size_t)N * 4);
    size_t ncur = (size_t)B * N + 1 + (size_t)B * NBKT;
    size_t o_ovf = alignup(o_cur + ncur * 4);
    size_t o_seg = alignup(o_ovf + (size_t)OVFCAP * 8);
    size_t o_hh = alignup(o_seg + (size_t)B * N * CAP * 4);
    size_t req = o_hh + nH * 2;
    size_t bkt_bytes = (size_t)B * NBKT * BKCAP * 8;   // lives in d_out
    bool radix_ok = bucketSz <= MAXBSZ && bkt_bytes <= (size_t)out_size * 4;

    if (ws_size >= req && N <= 65535 && B <= 65535) {
        int* g_inv = (int*)(w0 + o_inv);
        int* g_cursor = (int*)(w0 + o_cur);
        int* g_ovfcnt = g_cursor + (size_t)B * N;
        int* g_bktcnt = g_ovfcnt + 1;
        uint2* g_ovf = (uint2*)(w0 + o_ovf);
        unsigned* g_edges = (unsigned*)(w0 + o_seg);
        _Float16* Hh = (_Float16*)(w0 + o_hh);
        unsigned long long* g_bkt = (unsigned long long*)d_out;  // borrow d_out

        int nz = (int)ncur;
        int ninit = max(N, nz);
        k_init<<<(ninit + 255) / 256, 256, 0, stream>>>(nidx, g_inv, g_cursor, nz, N);

        if (radix_ok) {
            k_prep1<<<2048, 256, 0, stream>>>(
                (const fvec4*)H, (half4*)Hh, nH / 4,
                (const unsigned long long*)ei, ew, g_inv, g_bktcnt, g_bkt,
                B, E, N, bucketSz);
            k_pass2<<<B * NBKT, 256, 0, stream>>>(
                g_bkt, g_bktcnt, g_edges, g_cursor, g_ovfcnt, g_ovf, B, N, bucketSz);
        } else {
            k_prep_rs<<<2048, 256, 0, stream>>>(
                (const fvec4*)H, (half4*)Hh, nH / 4, 896, 1152,
                (const unsigned long long*)ei, ew, g_inv, g_cursor, g_edges,
                g_ovfcnt, g_ovf, B, E, N);
        }

        int groupsPerB = (N + 3) / 4;
        int xpb = (B > 0 && 8 % B == 0) ? 8 / B : 0;
        bool can_swz = xpb > 0 && (groupsPerB % xpb) == 0 &&
                       (((size_t)groupsPerB * B) % 8) == 0;
        if (can_swz) {
            k_agg_gap<<<groupsPerB * B, 256, 0, stream>>>(
                Hh, g_cursor, g_edges, out, B, N, xpb);
        } else {
            dim3 ag(groupsPerB, B);
            k_agg_gap<<<ag, 256, 0, stream>>>(Hh, g_cursor, g_edges, out, B, N, 0);
        }
        k_ovf<<<256, 256, 0, stream>>>(Hh, g_ovfcnt, g_ovf, out, N);
        return;
    }

    // ---- fallback: per-edge atomics ----
    int* finv = nullptr;
    if (ws_size >= (size_t)N * sizeof(int)) {
        finv = (int*)d_ws;
        k_init<<<(N + 255) / 256, 256, 0, stream>>>(nidx, finv, finv, 0, N);
    }
    size_t on = (size_t)out_size;
    k_zero_f32<<<(int)((on + 255) / 256), 256, 0, stream>>>(out, on);
    int blocks = (total * 64 + 255) / 256;
    k_atomic_agg<<<blocks, 256, 0, stream>>>(H, ei, ew, finv, out, B, E, N);
}

// Round 13
// 399.328 us; speedup vs baseline: 2.7594x; 2.7594x over previous
//
#include <hip/hip_runtime.h>

// Neighbor aggregation: out[b, dst] += w * H[b, src], H rows = 256 fp32.
// FINAL (= R9, best of 12 rounds, 401 us):
//  - gap scatter: cap-32 one-line segments per (b,dst), 4B records
//    (src u16 | w fp16); rare deg>32 edges -> overflow list, applied by
//    fp32-atomic fixup after the aggregate.
//  - H converted once to fp16 (halves gather traffic; absmax 0.125 vs 0.6225
//    threshold). Prep = persistent role-split kernel (896 cvt / 1152 scatter
//    blocks): cvt streams at BW share while scatter's atomic/coherence
//    latency overlaps across waves.
//  - aggregate: one wave per (b,node), XCD-partitioned flat grid, deg-masked
//    one-line segment read, 8-deep gather pipeline, fp32 acc, nt stores.
//    At its compulsory-miss wall: FETCH ~687MB @ ~4.1 TB/s L2-miss fabric.

constexpr int ROW = 256;        // HS*HS
constexpr int CAP = 32;         // records per (b,dst) segment = one 128B line
constexpr int OVFCAP = 262144;

typedef _Float16 half4 __attribute__((ext_vector_type(4)));
typedef float fvec4 __attribute__((ext_vector_type(4)));

static __device__ inline float h2f_bits(unsigned short u) {
    _Float16 h; __builtin_memcpy(&h, &u, 2); return (float)h;
}

__global__ void k_init(const int* __restrict__ nidx, int* __restrict__ inv,
                       int* __restrict__ zbuf, int nz, int N) {
    int i = blockIdx.x * blockDim.x + threadIdx.x;
    if (i < N) inv[nidx[i]] = i;
    if (i < nz) zbuf[i] = 0;
}

// Persistent fused prep: blocks [0, cvtBlocks) grid-stride convert H->fp16;
// remaining blocks grid-stride scatter edge records into cap-32 segments.
__global__ __launch_bounds__(256)
void k_prep(const fvec4* __restrict__ H, half4* __restrict__ Hh, size_t n4, int cvtBlocks,
            int scatBlocks,
            const unsigned long long* __restrict__ ei, const float* __restrict__ ew,
            const int* __restrict__ inv, int* __restrict__ cursor,
            unsigned* __restrict__ edges, int* __restrict__ ovfcnt,
            uint2* __restrict__ ovf, int B, int E, int N) {
    if ((int)blockIdx.x < cvtBlocks) {
        size_t stride = (size_t)cvtBlocks * 256;
        for (size_t i = (size_t)blockIdx.x * 256 + threadIdx.x; i < n4; i += stride) {
            fvec4 v = __builtin_nontemporal_load(&H[i]);
            half4 o;
            o.x = (_Float16)v.x; o.y = (_Float16)v.y;
            o.z = (_Float16)v.z; o.w = (_Float16)v.w;
            Hh[i] = o;   // cacheable: this IS the gather working set
        }
    } else {
        int total = B * E;
        int stride = scatBlocks * 256;
        for (int idx = ((int)blockIdx.x - cvtBlocks) * 256 + (int)threadIdx.x;
             idx < total; idx += stride) {
            unsigned long long pq = __builtin_nontemporal_load(&ei[idx]);
            int b = idx / E;
            int dst = inv[(int)(pq & 0xFFFFFFFFull)];
            int src = inv[(int)(pq >> 32)];
            float w = __builtin_nontemporal_load(&ew[idx]);
            _Float16 hw = (_Float16)w;
            unsigned short wb; __builtin_memcpy(&wb, &hw, 2);
            unsigned rec = (unsigned)(unsigned short)src | ((unsigned)wb << 16);
            size_t sidx = (size_t)b * N + dst;
            int pos = atomicAdd(&cursor[sidx], 1);
            if (pos < CAP) {
                __builtin_nontemporal_store(rec, &edges[sidx * CAP + pos]);
            } else {
                int op = atomicAdd(ovfcnt, 1);
                if (op < OVFCAP)
                    ovf[op] = make_uint2(((unsigned)b << 16) | (unsigned)dst, rec);
            }
        }
    }
}

__device__ inline void fma4(fvec4& acc, float w, half4 h) {
    acc.x += w * (float)h.x; acc.y += w * (float)h.y;
    acc.z += w * (float)h.z; acc.w += w * (float)h.w;
}

// xpb > 0: XCD-partitioned flat grid. xcd = bi&7 owns batch b = xcd/xpb;
// group index k = (bi>>3)*xpb + (xcd%xpb).
__global__ __launch_bounds__(256)
void k_agg_gap(const _Float16* __restrict__ Hh, const int* __restrict__ cursor,
               const unsigned* __restrict__ edges, float* __restrict__ out,
               int B, int N, int xpb) {
    int lane = threadIdx.x & 63;
    int wid = threadIdx.x >> 6;
    int b, grp;
    if (xpb > 0) {
        int bi = blockIdx.x;
        int xcd = bi & 7;
        b = xcd / xpb;
        grp = (bi >> 3) * xpb + (xcd % xpb);
    } else {
        b = blockIdx.y;
        grp = blockIdx.x;
    }
    int node = grp * 4 + wid;
    if (node >= N) return;
    size_t sidx = (size_t)b * N + node;
    int deg = cursor[sidx];
    if (deg > CAP) deg = CAP;
    const unsigned* seg = edges + sidx * CAP;
    unsigned rec = 0;
    if (lane < deg) rec = __builtin_nontemporal_load(&seg[lane]);  // one 128B line
    const half4* Hb = (const half4*)(Hh + (size_t)b * N * ROW);
    fvec4 acc = {0.f, 0.f, 0.f, 0.f};
    int j = 0;
    for (; j + 8 <= deg; j += 8) {
        int sv[8]; float wv[8];
#pragma unroll
        for (int u = 0; u < 8; ++u) {
            unsigned r = __shfl(rec, j + u);
            sv[u] = (int)(r & 0xFFFFu);
            wv[u] = h2f_bits((unsigned short)(r >> 16));
        }
        half4 hv[8];
#pragma unroll
        for (int u = 0; u < 8; ++u) hv[u] = Hb[(size_t)sv[u] * 64 + lane];
#pragma unroll
        for (int u = 0; u < 8; ++u) fma4(acc, wv[u], hv[u]);
    }
    if (j + 4 <= deg) {
        int sv[4]; float wv[4];
#pragma unroll
        for (int u = 0; u < 4; ++u) {
            unsigned r = __shfl(rec, j + u);
            sv[u] = (int)(r & 0xFFFFu);
            wv[u] = h2f_bits((unsigned short)(r >> 16));
        }
        half4 hv[4];
#pragma unroll
        for (int u = 0; u < 4; ++u) hv[u] = Hb[(size_t)sv[u] * 64 + lane];
#pragma unroll
        for (int u = 0; u < 4; ++u) fma4(acc, wv[u], hv[u]);
        j += 4;
    }
    for (; j < deg; ++j) {
        unsigned r = __shfl(rec, j);
        half4 h = Hb[(size_t)(r & 0xFFFFu) * 64 + lane];
        fma4(acc, h2f_bits((unsigned short)(r >> 16)), h);
    }
    __builtin_nontemporal_store(acc, (fvec4*)out + (sidx * 64 + lane));
}

// Apply rare cap-overflow edges with fp32 atomics (runs after k_agg_gap).
__global__ __launch_bounds__(256)
void k_ovf(const _Float16* __restrict__ Hh, const int* __restrict__ ovfcnt,
           const uint2* __restrict__ ovf, float* __restrict__ out, int N) {
    int lane = threadIdx.x & 63;
    int wv = (blockIdx.x * 256 + (int)threadIdx.x) >> 6;
    int nw = gridDim.x * 4;
    int count = *ovfcnt;
    if (count > OVFCAP) count = OVFCAP;
    for (int i = wv; i < count; i += nw) {
        uint2 v = ovf[i];
        int b = (int)(v.x >> 16);
        int dst = (int)(v.x & 0xFFFFu);
        int src = (int)(v.y & 0xFFFFu);
        float w = h2f_bits((unsigned short)(v.y >> 16));
        half4 h = ((const half4*)(Hh + (size_t)b * N * ROW))[(size_t)src * 64 + lane];
        float* op = out + ((size_t)b * N + dst) * ROW + lane * 4;
        atomicAdd(op + 0, w * (float)h.x);
        atomicAdd(op + 1, w * (float)h.y);
        atomicAdd(op + 2, w * (float)h.z);
        atomicAdd(op + 3, w * (float)h.w);
    }
}

// ---- minimal-workspace fallback ----
__global__ void k_zero_f32(float* __restrict__ p, size_t n) {
    size_t i = (size_t)blockIdx.x * blockDim.x + threadIdx.x;
    if (i < n) p[i] = 0.f;
}

__global__ void k_atomic_agg(const float* __restrict__ H, const int* __restrict__ ei,
                             const float* __restrict__ ew, const int* __restrict__ inv,
                             float* __restrict__ out, int B, int E, int N) {
    int lane = threadIdx.x & 63;
    int widx = (blockIdx.x * blockDim.x + threadIdx.x) >> 6;
    int total = B * E;
    if (widx >= total) return;
    int b = widx / E;
    int d = ei[(size_t)widx * 2];
    int s = ei[(size_t)widx * 2 + 1];
    if (inv) { d = inv[d]; s = inv[s]; }
    float w = ew[widx];
    const float4* hp = (const float4*)(H + ((size_t)b * N + s) * ROW);
    float4 h = hp[lane];
    float* op = out + ((size_t)b * N + d) * ROW + lane * 4;
    atomicAdd(op + 0, w * h.x);
    atomicAdd(op + 1, w * h.y);
    atomicAdd(op + 2, w * h.z);
    atomicAdd(op + 3, w * h.w);
}

static inline size_t alignup(size_t x) { return (x + 255) & ~(size_t)255; }

extern "C" void kernel_launch(void* const* d_in, const int* in_sizes, int n_in,
                              void* d_out, int out_size, void* d_ws, size_t ws_size,
                              hipStream_t stream) {
    const float* H = (const float*)d_in[0];
    const int* ei = (const int*)d_in[1];
    const float* ew = (const float*)d_in[2];
    const int* nidx = (const int*)d_in[3];
    float* out = (float*)d_out;

    int N = in_sizes[3];                    // 50000
    int B = in_sizes[0] / (N * ROW);        // 4
    int E = in_sizes[2] / B;                // 800000
    int total = B * E;
    size_t nH = (size_t)B * N * ROW;
    char* w0 = (char*)d_ws;

    // ---- workspace layout: inv | cursor(B*N)+ovfcnt | ovf | segments | Hh ----
    size_t o_inv = 0;
    size_t o_cur = alignup(o_inv + (size_t)N * 4);
    size_t ncur = (size_t)B * N + 1;                      // cursors + ovfcnt
    size_t o_ovf = alignup(o_cur + ncur * 4);
    size_t o_seg = alignup(o_ovf + (size_t)OVFCAP * 8);
    size_t o_hh = alignup(o_seg + (size_t)B * N * CAP * 4);
    size_t req = o_hh + nH * 2;

    if (ws_size >= req && N <= 65535 && B <= 65535) {
        int* g_inv = (int*)(w0 + o_inv);
        int* g_cursor = (int*)(w0 + o_cur);
        int* g_ovfcnt = g_cursor + (size_t)B * N;
        uint2* g_ovf = (uint2*)(w0 + o_ovf);
        unsigned* g_edges = (unsigned*)(w0 + o_seg);
        _Float16* Hh = (_Float16*)(w0 + o_hh);

        int nz = (int)ncur;
        int ninit = max(N, nz);
        k_init<<<(ninit + 255) / 256, 256, 0, stream>>>(nidx, g_inv, g_cursor, nz, N);
        int cvtBlocks = 896, scatBlocks = 1152;   // persistent full residency
        k_prep<<<cvtBlocks + scatBlocks, 256, 0, stream>>>(
            (const fvec4*)H, (half4*)Hh, nH / 4, cvtBlocks, scatBlocks,
            (const unsigned long long*)ei, ew, g_inv, g_cursor, g_edges,
            g_ovfcnt, g_ovf, B, E, N);

        int groupsPerB = (N + 3) / 4;
        int xpb = (B > 0 && 8 % B == 0) ? 8 / B : 0;
        bool can_swz = xpb > 0 && (groupsPerB % xpb) == 0 &&
                       (((size_t)groupsPerB * B) % 8) == 0;
        if (can_swz) {
            k_agg_gap<<<groupsPerB * B, 256, 0, stream>>>(
                Hh, g_cursor, g_edges, out, B, N, xpb);
        } else {
            dim3 ag(groupsPerB, B);
            k_agg_gap<<<ag, 256, 0, stream>>>(Hh, g_cursor, g_edges, out, B, N, 0);
        }
        k_ovf<<<256, 256, 0, stream>>>(Hh, g_ovfcnt, g_ovf, out, N);
        return;
    }

    // ---- fallback: per-edge atomics ----
    int* finv = nullptr;
    if (ws_size >= (size_t)N * sizeof(int)) {
        finv = (int*)d_ws;
        k_init<<<(N + 255) / 256, 256, 0, stream>>>(nidx, finv, finv, 0, N);
    }
    size_t on = (size_t)out_size;
    k_zero_f32<<<(int)((on + 255) / 256), 256, 0, stream>>>(out, on);
    int blocks = (total * 64 + 255) / 256;
    k_atomic_agg<<<blocks, 256, 0, stream>>>(H, ei, ew, finv, out, B, E, N);
}